// Round 14
// baseline (128.886 us; speedup 1.0000x reference)
//
#include <hip/hip_runtime.h>
#include <hip/hip_bf16.h>

typedef float    f4    __attribute__((ext_vector_type(4)));
typedef short    s8v   __attribute__((ext_vector_type(8)));
typedef __bf16   bf8v  __attribute__((ext_vector_type(8)));
typedef unsigned int u32x4v __attribute__((ext_vector_type(4)));
typedef int      i4    __attribute__((ext_vector_type(4)));
typedef unsigned short u16;

typedef const __attribute__((address_space(1))) void GAS;
typedef __attribute__((address_space(3))) void LAS;

#define NB 8
#define NN 256
#define ND 128
#define SB0() __builtin_amdgcn_sched_barrier(0)

static __device__ __forceinline__ u16 f2bf(float f) {
    union { float f; unsigned u; } v; v.f = f;
    unsigned r = v.u + 0x7FFF + ((v.u >> 16) & 1);   // RNE
    return (u16)(r >> 16);
}

static __device__ __forceinline__ unsigned pack2bf(float a, float b) {
    unsigned ua = __builtin_bit_cast(unsigned, a) + 0x8000u;
    unsigned ub = __builtin_bit_cast(unsigned, b) + 0x8000u;
    return __builtin_amdgcn_perm(ub, ua, 0x07060302u);
}

// ---------------- precompute: P = x@W1a + b1m, Qp2 per-lane layout, pack W1c
// Qp2[ (((b*16+gc)*4+colq)*64 + lane)*8 + half*4 + r ]
//   = (x_j @ W1b)[colq*32 + half*16 + (lane&15)], j = gc*16 + (lane>>4)*4 + r
__global__ __launch_bounds__(256) void prep_kernel(
    const float* __restrict__ x, const float* __restrict__ W1m,
    const float* __restrict__ b1m,
    float* __restrict__ P, float* __restrict__ Qp2, u16* __restrict__ W1cp)
{
    if (blockIdx.x == 1024) {
        for (int idx = threadIdx.x; idx < 16384; idx += 256) {
            int e  = idx & 7;
            int ln = (idx >> 3) & 63;
            int nt = (idx >> 9) & 7;
            int kt = idx >> 12;
            int k  = kt * 32 + (ln >> 4) * 8 + e;
            int d  = nt * 16 + (ln & 15);
            W1cp[idx] = f2bf(W1m[(2 * ND + k) * ND + d]);
        }
        return;
    }
    __shared__ float xl[256];
    int t = threadIdx.x;
    int row0 = blockIdx.x * 2;
    xl[t] = x[row0 * ND + t];
    __syncthreads();
    int r2 = t >> 7;
    int d = t & 127;
    int row = row0 + r2;
    float sp = b1m[d], sq = 0.f;
    const float* xr = &xl[r2 * ND];
    #pragma unroll 8
    for (int k = 0; k < ND; ++k) {
        float xv = xr[k];
        sp += xv * W1m[k * ND + d];
        sq += xv * W1m[(ND + k) * ND + d];
    }
    P[row * ND + d] = sp;
    int b   = row >> 8;
    int j   = row & 255;
    int gc  = j >> 4;
    int lgq = (j & 15) >> 2;
    int r   = j & 3;
    int colq = d >> 5;
    int half = (d >> 4) & 1;
    int lane = lgq * 16 + (d & 15);
    Qp2[((((size_t)b * 16 + gc) * 4 + colq) * 64 + lane) * 8 + half * 4 + r] = sq;
}

// ---------------- edge kernel: 8192 ONE-WAVE blocks. Block = (b, i, colq):
// wave owns 32 output cols x all 256 j (16 chunks). Private 2x8KB LDS staging
// via global_load_lds (src-swizzled f32), ZERO barriers, exact per-wave vmcnt.
__global__ __launch_bounds__(64, 4) void edge_kernel(
    const float* __restrict__ edge0, const int* __restrict__ mask,
    const float* __restrict__ P, const float* __restrict__ Qp2,
    const u16* __restrict__ W1cp,
    float* __restrict__ aggP)
{
    __shared__ float ebuf[2][2048];   // 2 x 8KB raw f32 chunk buffers (private)

    // b == XCD; 4 colq siblings of (b,i) within 32 blockIdx -> same-XCD L2 share
    const int b    = blockIdx.x & 7;
    const int k    = blockIdx.x >> 3;
    const int i    = k >> 2;
    const int colq = k & 3;
    const int bid  = b * 256 + i;

    const int lane = threadIdx.x;     // 0..63 (one wave)
    const int l15  = lane & 15;
    const int lg   = lane >> 4;

    const char* e0c = (const char*)(edge0 + (size_t)bid * (NN * ND));

    // B fragments: 4 kt x 2 n for cols colq*32 + n*16 + l15 (32 VGPR)
    s8v bfr[4][2];
    #pragma unroll
    for (int kt = 0; kt < 4; ++kt)
        #pragma unroll
        for (int n = 0; n < 2; ++n)
            bfr[kt][n] = *reinterpret_cast<const s8v*>(
                &W1cp[(((kt * 8) + (colq * 2 + n)) * 64 + lane) * 8]);

    const int col0 = colq * 32 + l15;
    const float pv0 = P[bid * ND + col0];
    const float pv1 = P[bid * ND + col0 + 16];

    auto STAGE = [&](int cc, int bb) {
        const char* cb = e0c + (size_t)cc * 8192;
        #pragma unroll
        for (int u = 0; u < 8; ++u) {
            int row  = u * 2 + (lane >> 5);
            int colb = (lane & 31) * 16;
            const char* g = cb + row * 512 + (colb ^ ((row & 7) << 4));
            __builtin_amdgcn_global_load_lds(
                (GAS*)g, (LAS*)&ebuf[bb][u * 256], 16, 0, 0);
        }
    };
    f4 qg[2][2];
    i4 mg[2];
    auto LOADQM = [&](int cc, int g) {
        const f4* qp = reinterpret_cast<const f4*>(
            Qp2 + ((((size_t)b * 16 + cc) * 4 + colq) * 64 + lane) * 8);
        qg[g][0] = qp[0];
        qg[g][1] = qp[1];
        mg[g] = *reinterpret_cast<const i4*>(mask + bid * NN + cc * 16 + lg * 4);
    };

    float agg0 = 0.f, agg1 = 0.f;

    // prologue: queue entering iter0 = [S0(8), QM0(3), S1(8)]
    STAGE(0, 0); SB0();
    LOADQM(0, 0); SB0();
    STAGE(1, 1); SB0();

    #pragma unroll
    for (int c = 0; c < 16; ++c) {
        const int cur = c & 1;
        if (c < 15) { LOADQM(c + 1, cur ^ 1); SB0(); }
        // steady: 22 outstanding -> drain exactly S_c; tail: 11 -> drain S_15
        if (c < 15) asm volatile("s_waitcnt vmcnt(14)" ::: "memory");
        else        asm volatile("s_waitcnt vmcnt(3)"  ::: "memory");
        SB0();
        // read chunk c (f32, swizzled) + pack to bf16 A-frags
        const char* bufc = (const char*)&ebuf[cur][0];
        const int rb  = l15 * 512;
        const int swz = (l15 & 7) << 4;
        s8v apk[4];
        #pragma unroll
        for (int kt = 0; kt < 4; ++kt) {
            int cbyte = kt * 128 + lg * 32;
            f4 a0 = *reinterpret_cast<const f4*>(bufc + rb + ((cbyte)      ^ swz));
            f4 a1 = *reinterpret_cast<const f4*>(bufc + rb + ((cbyte + 16) ^ swz));
            u32x4v aw;
            aw[0] = pack2bf(a0[0], a0[1]);
            aw[1] = pack2bf(a0[2], a0[3]);
            aw[2] = pack2bf(a1[0], a1[1]);
            aw[3] = pack2bf(a1[2], a1[3]);
            apk[kt] = __builtin_bit_cast(s8v, aw);
        }
        asm volatile("s_waitcnt lgkmcnt(0)" ::: "memory");   // reads retired
        SB0();
        if (c < 14) { STAGE(c + 2, cur); SB0(); }            // reuse buf cur: safe
        // MFMA + agg
        f4 acc0 = {0.f, 0.f, 0.f, 0.f};
        f4 acc1 = {0.f, 0.f, 0.f, 0.f};
        #pragma unroll
        for (int kt = 0; kt < 4; ++kt) {
            acc0 = __builtin_amdgcn_mfma_f32_16x16x32_bf16(
                __builtin_bit_cast(bf8v, apk[kt]), __builtin_bit_cast(bf8v, bfr[kt][0]), acc0, 0, 0, 0);
            acc1 = __builtin_amdgcn_mfma_f32_16x16x32_bf16(
                __builtin_bit_cast(bf8v, apk[kt]), __builtin_bit_cast(bf8v, bfr[kt][1]), acc1, 0, 0, 0);
        }
        #pragma unroll
        for (int r = 0; r < 4; ++r) {
            float mk = (float)mg[cur][r];
            float h0 = fmaxf(acc0[r] + pv0 + qg[cur][0][r], 0.f);
            float h1 = fmaxf(acc1[r] + pv1 + qg[cur][1][r], 0.f);
            agg0 += mk * h0;
            agg1 += mk * h1;
        }
    }

    // reduce over the 4 row-groups; lanes lg==0 hold final col sums
    agg0 += __shfl_xor(agg0, 16); agg0 += __shfl_xor(agg0, 32);
    agg1 += __shfl_xor(agg1, 16); agg1 += __shfl_xor(agg1, 32);
    if (lg == 0) {
        aggP[(size_t)bid * ND + col0]      = agg0;
        aggP[(size_t)bid * ND + col0 + 16] = agg1;
    }
}

// ---------------- tail kernel: 256 blocks x 8 nodes. Weights read once per
// block (8-node reuse): W2m-fold, update MLP, residual, LayerNorm.
__global__ __launch_bounds__(256) void tail_kernel(
    const float* __restrict__ x, const int* __restrict__ mask,
    const float* __restrict__ aggP,
    const float* __restrict__ W2m, const float* __restrict__ b2m,
    const float* __restrict__ W1u, const float* __restrict__ b1u,
    const float* __restrict__ W2u, const float* __restrict__ b2u,
    const float* __restrict__ gamma, const float* __restrict__ beta,
    float* __restrict__ out)
{
    __shared__ float ah[8][ND], xr[8][ND], am[8][ND], hu[8][ND], yl[8][ND];
    __shared__ float cl[8];
    const int tid = threadIdx.x;
    const int blk = blockIdx.x;

    // load aggH + x rows (coalesced f4)
    {
        const f4* sa = reinterpret_cast<const f4*>(aggP + (size_t)blk * 1024);
        const f4* sx = reinterpret_cast<const f4*>(x + (size_t)blk * 1024);
        reinterpret_cast<f4*>(&ah[0][0])[tid] = sa[tid];
        reinterpret_cast<f4*>(&xr[0][0])[tid] = sx[tid];
    }
    // cnt per node (32 threads each)
    {
        int node = tid >> 5, t32 = tid & 31;
        const int* mrow = mask + ((size_t)blk * 8 + node) * NN;
        int s = 0;
        #pragma unroll
        for (int jj = 0; jj < 8; ++jj) s += mrow[t32 + jj * 32];
        s += __shfl_xor(s, 16); s += __shfl_xor(s, 8);
        s += __shfl_xor(s, 4);  s += __shfl_xor(s, 2); s += __shfl_xor(s, 1);
        if (t32 == 0) cl[node] = (float)s;
    }
    __syncthreads();

    const int d  = tid & 127;
    const int ng = tid >> 7;     // handles nodes 4ng..4ng+3

    // am = (ah @ W2m + cnt*b2m) / (cnt+eps)
    {
        float s0 = 0.f, s1 = 0.f, s2 = 0.f, s3 = 0.f;
        #pragma unroll 4
        for (int kk = 0; kk < ND; ++kk) {
            float w = W2m[kk * ND + d];
            s0 += ah[ng * 4 + 0][kk] * w;
            s1 += ah[ng * 4 + 1][kk] * w;
            s2 += ah[ng * 4 + 2][kk] * w;
            s3 += ah[ng * 4 + 3][kk] * w;
        }
        float bb = b2m[d];
        am[ng * 4 + 0][d] = (s0 + cl[ng * 4 + 0] * bb) / (cl[ng * 4 + 0] + 1e-6f);
        am[ng * 4 + 1][d] = (s1 + cl[ng * 4 + 1] * bb) / (cl[ng * 4 + 1] + 1e-6f);
        am[ng * 4 + 2][d] = (s2 + cl[ng * 4 + 2] * bb) / (cl[ng * 4 + 2] + 1e-6f);
        am[ng * 4 + 3][d] = (s3 + cl[ng * 4 + 3] * bb) / (cl[ng * 4 + 3] + 1e-6f);
    }
    __syncthreads();
    // hu = relu([x, am] @ W1u + b1u)
    {
        float bb = b1u[d];
        float s0 = bb, s1 = bb, s2 = bb, s3 = bb;
        #pragma unroll 4
        for (int kk = 0; kk < ND; ++kk) {
            float w = W1u[kk * ND + d];
            s0 += xr[ng * 4 + 0][kk] * w;
            s1 += xr[ng * 4 + 1][kk] * w;
            s2 += xr[ng * 4 + 2][kk] * w;
            s3 += xr[ng * 4 + 3][kk] * w;
        }
        #pragma unroll 4
        for (int kk = 0; kk < ND; ++kk) {
            float w = W1u[(ND + kk) * ND + d];
            s0 += am[ng * 4 + 0][kk] * w;
            s1 += am[ng * 4 + 1][kk] * w;
            s2 += am[ng * 4 + 2][kk] * w;
            s3 += am[ng * 4 + 3][kk] * w;
        }
        hu[ng * 4 + 0][d] = fmaxf(s0, 0.f);
        hu[ng * 4 + 1][d] = fmaxf(s1, 0.f);
        hu[ng * 4 + 2][d] = fmaxf(s2, 0.f);
        hu[ng * 4 + 3][d] = fmaxf(s3, 0.f);
    }
    __syncthreads();
    // yl = x + hu @ W2u + b2u
    {
        float bb = b2u[d];
        float s0 = bb, s1 = bb, s2 = bb, s3 = bb;
        #pragma unroll 4
        for (int kk = 0; kk < ND; ++kk) {
            float w = W2u[kk * ND + d];
            s0 += hu[ng * 4 + 0][kk] * w;
            s1 += hu[ng * 4 + 1][kk] * w;
            s2 += hu[ng * 4 + 2][kk] * w;
            s3 += hu[ng * 4 + 3][kk] * w;
        }
        yl[ng * 4 + 0][d] = xr[ng * 4 + 0][d] + s0;
        yl[ng * 4 + 1][d] = xr[ng * 4 + 1][d] + s1;
        yl[ng * 4 + 2][d] = xr[ng * 4 + 2][d] + s2;
        yl[ng * 4 + 3][d] = xr[ng * 4 + 3][d] + s3;
    }
    __syncthreads();
    // LayerNorm: node = tid>>5, each thread owns 4 dims
    {
        int node = tid >> 5, t32 = tid & 31;
        f4 v = *reinterpret_cast<const f4*>(&yl[node][t32 * 4]);
        float s1 = v[0] + v[1] + v[2] + v[3];
        float s2 = v[0]*v[0] + v[1]*v[1] + v[2]*v[2] + v[3]*v[3];
        s1 += __shfl_xor(s1, 16); s2 += __shfl_xor(s2, 16);
        s1 += __shfl_xor(s1, 8);  s2 += __shfl_xor(s2, 8);
        s1 += __shfl_xor(s1, 4);  s2 += __shfl_xor(s2, 4);
        s1 += __shfl_xor(s1, 2);  s2 += __shfl_xor(s2, 2);
        s1 += __shfl_xor(s1, 1);  s2 += __shfl_xor(s2, 1);
        float mu  = s1 * (1.f / 128.f);
        float ex2 = s2 * (1.f / 128.f);
        float rs  = rsqrtf(ex2 - mu * mu + 1e-5f);
        float* orow = out + ((size_t)blk * 8 + node) * ND + t32 * 4;
        #pragma unroll
        for (int e = 0; e < 4; ++e) {
            int dd = t32 * 4 + e;
            orow[e] = (v[e] - mu) * rs * gamma[dd] + beta[dd];
        }
    }
}

extern "C" void kernel_launch(void* const* d_in, const int* in_sizes, int n_in,
                              void* d_out, int out_size, void* d_ws, size_t ws_size,
                              hipStream_t stream) {
    (void)in_sizes; (void)n_in; (void)out_size; (void)ws_size;
    const float* x     = (const float*)d_in[0];
    const float* edge0 = (const float*)d_in[1];
    const int*   mask  = (const int*)d_in[2];
    const float* W1m   = (const float*)d_in[3];
    const float* b1m   = (const float*)d_in[4];
    const float* W2m   = (const float*)d_in[5];
    const float* b2m   = (const float*)d_in[6];
    const float* W1u   = (const float*)d_in[7];
    const float* b1u   = (const float*)d_in[8];
    const float* W2u   = (const float*)d_in[9];
    const float* b2u   = (const float*)d_in[10];
    const float* gamma = (const float*)d_in[11];
    const float* beta  = (const float*)d_in[12];

    float* P    = (float*)d_ws;                   // 2048*128 f32 = 1 MB
    float* Qp2  = P + 2048 * 128;                 // 1 MB (per-lane fused layout)
    u16*   W1cp = (u16*)(Qp2 + 2048 * 128);       // 32 KB
    float* aggP = (float*)(W1cp + 16384);         // 2048*128 f32 = 1 MB

    float* o = (float*)d_out;

    prep_kernel<<<dim3(1025), dim3(256), 0, stream>>>(x, W1m, b1m, P, Qp2, W1cp);
    edge_kernel<<<dim3(8192), dim3(64), 0, stream>>>(edge0, mask, P, Qp2, W1cp, aggP);
    tail_kernel<<<dim3(256), dim3(256), 0, stream>>>(
        x, mask, aggP, W2m, b2m, W1u, b1u, W2u, b2u, gamma, beta, o);
}

// Round 15
// 80.549 us; speedup vs baseline: 1.6001x; 1.6001x over previous
//
#include <hip/hip_runtime.h>
#include <hip/hip_bf16.h>

typedef float    f4    __attribute__((ext_vector_type(4)));
typedef short    s8v   __attribute__((ext_vector_type(8)));
typedef __bf16   bf8v  __attribute__((ext_vector_type(8)));
typedef unsigned int u32x4v __attribute__((ext_vector_type(4)));
typedef unsigned short u16;

#define NB 8
#define NN 256
#define ND 128

static __device__ __forceinline__ u16 f2bf(float f) {
    union { float f; unsigned u; } v; v.f = f;
    unsigned r = v.u + 0x7FFF + ((v.u >> 16) & 1);   // RNE
    return (u16)(r >> 16);
}

// pack two f32 -> two bf16 (round-half-up via +0x8000, then v_perm pack)
static __device__ __forceinline__ unsigned pack2bf(float a, float b) {
    unsigned ua = __builtin_bit_cast(unsigned, a) + 0x8000u;
    unsigned ub = __builtin_bit_cast(unsigned, b) + 0x8000u;
    return __builtin_amdgcn_perm(ub, ua, 0x07060302u);
}

// ---------------- precompute: P = x@W1a + b1m, Qn[b*256+j][d] = (x@W1b)[d], pack W1c
__global__ __launch_bounds__(256) void prep_kernel(
    const float* __restrict__ x, const float* __restrict__ W1m,
    const float* __restrict__ b1m,
    float* __restrict__ P, float* __restrict__ Qn, u16* __restrict__ W1cp)
{
    if (blockIdx.x == 1024) {
        // pack W1c (rows 256..383 of W1m) into MFMA B-fragment order
        for (int idx = threadIdx.x; idx < 16384; idx += 256) {
            int e  = idx & 7;
            int ln = (idx >> 3) & 63;
            int nt = (idx >> 9) & 7;
            int kt = idx >> 12;
            int k  = kt * 32 + (ln >> 4) * 8 + e;
            int d  = nt * 16 + (ln & 15);
            W1cp[idx] = f2bf(W1m[(2 * ND + k) * ND + d]);
        }
        return;
    }
    __shared__ float xl[256];
    int t = threadIdx.x;
    int row0 = blockIdx.x * 2;
    xl[t] = x[row0 * ND + t];
    __syncthreads();
    int r = t >> 7;
    int d = t & 127;
    int row = row0 + r;
    float sp = b1m[d], sq = 0.f;
    const float* xr = &xl[r * ND];
    #pragma unroll 8
    for (int k = 0; k < ND; ++k) {
        float xv = xr[k];
        sp += xv * W1m[k * ND + d];
        sq += xv * W1m[(ND + k) * ND + d];
    }
    P[row * ND + d] = sp;
    Qn[row * ND + d] = sq;          // row-major: coalesced reads in fused kernel
}

// ---------------- fused: per-block (b,i). 16 chunks x 16 rows.
// R9 structure (82us) + Q 1-iter-ahead register prefetch: the agg phase consumes
// registers that landed last iteration, removing the only zero-slack load wait
// from the loop critical path. Exact in-order vmcnt ledger preserved.
__global__ __launch_bounds__(256, 5) void fused_kernel(
    const float* __restrict__ x, const float* __restrict__ edge0,
    const int* __restrict__ mask,
    const float* __restrict__ W2m, const float* __restrict__ b2m,
    const float* __restrict__ W1u, const float* __restrict__ b1u,
    const float* __restrict__ W2u, const float* __restrict__ b2u,
    const float* __restrict__ gamma, const float* __restrict__ beta,
    const float* __restrict__ P, const float* __restrict__ Qn,
    const u16* __restrict__ W1cp,
    float* __restrict__ out)
{
    __shared__ float ebuf[3][1024];   // 3 x 4KB bf16 chunk buffers (16 rows x 128 bf16)
    __shared__ float ml[NN];
    __shared__ float xrow[ND];
    __shared__ float redc[4], redA[4], redB[4];

    // tail scratch carved from ebuf[1] (last read of buf1: chunk 13)
    float* aggH = &ebuf[1][0];
    float* am   = &ebuf[1][128];
    float* hu   = &ebuf[1][256];
    float* yl   = &ebuf[1][384];

    // bijective XCD swizzle: XCD k owns batch k
    const int bid  = (blockIdx.x & 7) * 256 + (blockIdx.x >> 3);
    const int b    = bid >> 8;
    const int tid  = threadIdx.x;
    const int wave = tid >> 6;
    const int lane = tid & 63;
    const int l15  = lane & 15;
    const int lg   = lane >> 4;

    const char* e0c = (const char*)(edge0 + (size_t)bid * (NN * ND));

    float mval = (float)mask[bid * NN + tid];
    ml[tid] = mval;
    if (tid < ND) xrow[tid] = x[bid * ND + tid];

    // B fragments: this wave's 2 col-tiles x 4 k-tiles (32 VGPR)
    s8v bfr[4][2];
    #pragma unroll
    for (int kt = 0; kt < 4; ++kt)
        #pragma unroll
        for (int n = 0; n < 2; ++n)
            bfr[kt][n] = *reinterpret_cast<const s8v*>(
                &W1cp[(((kt * 8) + (wave * 2 + n)) * 64 + lane) * 8]);

    const int col0 = wave * 32 + l15;
    const float pv0 = P[bid * ND + col0];
    const float pv1 = P[bid * ND + col0 + 16];
    // Qn row base for this lane: row j = c*16 + lg*4 + r, element col0 (+16)
    const float* qbase = Qn + ((size_t)b * NN + lg * 4) * ND + col0;

    // staging geometry: thread t owns 8 consecutive f32 of the chunk
    const int srow  = tid >> 4;
    const int swoff = srow * 256 + (((tid & 15) * 16) ^ ((srow & 7) << 4));

    auto LOADE = [&](int cc, f4* er) {
        const char* cb = e0c + (size_t)cc * 8192 + tid * 32;
        er[0] = *reinterpret_cast<const f4*>(cb);
        er[1] = *reinterpret_cast<const f4*>(cb + 16);
    };
    auto WRITEE = [&](const f4* er, int bb) {
        u32x4v aw;
        aw[0] = pack2bf(er[0][0], er[0][1]);
        aw[1] = pack2bf(er[0][2], er[0][3]);
        aw[2] = pack2bf(er[1][0], er[1][1]);
        aw[3] = pack2bf(er[1][2], er[1][3]);
        *reinterpret_cast<u32x4v*>(
            reinterpret_cast<char*>(&ebuf[bb][0]) + swoff) = aw;
    };

    float agg0 = 0.f, agg1 = 0.f;
    f4 eA[2], eB[2];              // two E generations (even chunks -> eA, odd -> eB)
    float qg[2][2][4];            // two Q generations x {col0, col0+16} x 4 rows

    auto LOADQ = [&](int cc, int gen) {
        const float* qr = qbase + (size_t)cc * 16 * ND;
        #pragma unroll
        for (int r = 0; r < 4; ++r) {
            qg[gen][0][r] = qr[r * ND];
            qg[gen][1][r] = qr[r * ND + 16];
        }
    };

    // prologue: Q_0 (8 dwords), E_0 (2), E_1 (2); drain through E_0; stage chunk 0
    LOADQ(0, 0);
    __builtin_amdgcn_sched_barrier(0);
    LOADE(0, eA);
    __builtin_amdgcn_sched_barrier(0);
    LOADE(1, eB);
    __builtin_amdgcn_sched_barrier(0);
    asm volatile("s_waitcnt vmcnt(2)" ::: "memory");   // E_0 + Q_0 + older done; E_1 in flight
    WRITEE(eA, 0);
    asm volatile("s_waitcnt lgkmcnt(0)" ::: "memory");

    #pragma unroll
    for (int c = 0; c < 16; ++c) {
        // top barrier: chunk c's LDS writes visible to all waves
        __builtin_amdgcn_s_barrier();
        __builtin_amdgcn_sched_barrier(0);
        // issue Q_{c+1} (prefetch, consumed next iter) BEFORE E_{c+2}
        if (c < 15) {
            LOADQ(c + 1, (c + 1) & 1);
            __builtin_amdgcn_sched_barrier(0);
        }
        if (c < 14) {
            if (c & 1) LOADE(c + 2, eA); else LOADE(c + 2, eB);
            __builtin_amdgcn_sched_barrier(0);
        }
        // ---- compute chunk c from bf16 buf[c%3]; Q_c already in registers ----
        const char* bufc = (const char*)&ebuf[c % 3][0];
        const int rb  = l15 * 256;
        const int swz = (l15 & 7) << 4;
        f4 acc0 = {0.f, 0.f, 0.f, 0.f};
        f4 acc1 = {0.f, 0.f, 0.f, 0.f};
        #pragma unroll
        for (int kt = 0; kt < 4; ++kt) {
            s8v av = *reinterpret_cast<const s8v*>(
                bufc + rb + ((kt * 64 + lg * 16) ^ swz));
            acc0 = __builtin_amdgcn_mfma_f32_16x16x32_bf16(
                __builtin_bit_cast(bf8v, av), __builtin_bit_cast(bf8v, bfr[kt][0]), acc0, 0, 0, 0);
            acc1 = __builtin_amdgcn_mfma_f32_16x16x32_bf16(
                __builtin_bit_cast(bf8v, av), __builtin_bit_cast(bf8v, bfr[kt][1]), acc1, 0, 0, 0);
        }
        // rows j = c*16 + lg*4 + r; mask + P + Q(reg) + relu + agg — no load wait
        f4 mk = *reinterpret_cast<const f4*>(&ml[c * 16 + lg * 4]);
        const int g = c & 1;
        #pragma unroll
        for (int r = 0; r < 4; ++r) {
            float h0 = fmaxf(acc0[r] + pv0 + qg[g][0][r], 0.f);
            float h1 = fmaxf(acc1[r] + pv1 + qg[g][1][r], 0.f);
            agg0 += mk[r] * h0;
            agg1 += mk[r] * h1;
        }
        __builtin_amdgcn_sched_barrier(0);
        // ---- stage chunk c+1 into buf (c+1)%3 ----
        // queue (oldest->newest): E_{c+1}(2), Q_{c+1}(8), E_{c+2}(2)
        if (c < 15) {
            if (c < 14)
                asm volatile("s_waitcnt vmcnt(10)" ::: "memory"); // drain exactly E_{c+1}
            else
                asm volatile("s_waitcnt vmcnt(8)" ::: "memory");  // c=14: no E_16 issued
            if (c & 1) WRITEE(eA, (c + 1) % 3); else WRITEE(eB, (c + 1) % 3);
            asm volatile("s_waitcnt lgkmcnt(0)" ::: "memory");
            __builtin_amdgcn_sched_barrier(0);
        }
    }

    // reduce agg partials across the 4 row-groups
    agg0 += __shfl_xor(agg0, 16); agg0 += __shfl_xor(agg0, 32);
    agg1 += __shfl_xor(agg1, 16); agg1 += __shfl_xor(agg1, 32);
    // cnt = sum(mask)
    float cv = mval;
    #pragma unroll
    for (int o = 32; o > 0; o >>= 1) cv += __shfl_xor(cv, o);
    if (lane == 0) redc[wave] = cv;
    __syncthreads();   // main loop fully done; tail carve of ebuf[1] now safe
    if (lg == 0) {
        aggH[wave * 32 + l15]      = agg0;
        aggH[wave * 32 + 16 + l15] = agg1;
    }
    __syncthreads();

    const float cnt = redc[0] + redc[1] + redc[2] + redc[3];
    const float inv = 1.f / (cnt + 1e-6f);
    const int d  = tid & 127;
    const int hf = tid >> 7;

    // agg_msg = (aggH @ W2m + cnt*b2m) / (cnt+eps)
    {
        float s = 0.f;
        #pragma unroll 8
        for (int k = hf * 64; k < hf * 64 + 64; ++k) s += aggH[k] * W2m[k * ND + d];
        ml[tid] = s;
    }
    __syncthreads();
    if (tid < ND) am[d] = (ml[d] + ml[d + ND] + cnt * b2m[d]) * inv;
    __syncthreads();
    // hu = relu([x, agg] @ W1u + b1u)
    {
        float s = 0.f;
        const float* W = W1u + (size_t)hf * ND * ND;
        const float* v = hf ? am : xrow;
        #pragma unroll 8
        for (int k = 0; k < ND; ++k) s += v[k] * W[k * ND + d];
        ml[tid] = s;
    }
    __syncthreads();
    if (tid < ND) hu[d] = fmaxf(ml[d] + ml[d + ND] + b1u[d], 0.f);
    __syncthreads();
    // y = x + hu @ W2u + b2u
    {
        float s = 0.f;
        #pragma unroll 8
        for (int k = hf * 64; k < hf * 64 + 64; ++k) s += hu[k] * W2u[k * ND + d];
        ml[tid] = s;
    }
    __syncthreads();
    if (tid < ND) yl[d] = xrow[d] + ml[d] + ml[d + ND] + b2u[d];
    __syncthreads();
    // LayerNorm
    float yv = (tid < ND) ? yl[tid] : 0.f;
    float s1 = yv, s2 = yv * yv;
    #pragma unroll
    for (int o = 32; o > 0; o >>= 1) { s1 += __shfl_xor(s1, o); s2 += __shfl_xor(s2, o); }
    if (lane == 0) { redA[wave] = s1; redB[wave] = s2; }
    __syncthreads();
    if (tid < ND) {
        float mu  = (redA[0] + redA[1] + redA[2] + redA[3]) * (1.f / 128.f);
        float ex2 = (redB[0] + redB[1] + redB[2] + redB[3]) * (1.f / 128.f);
        float var = ex2 - mu * mu;
        float rs  = rsqrtf(var + 1e-5f);
        out[bid * ND + d] = (yl[d] - mu) * rs * gamma[d] + beta[d];
    }
}

extern "C" void kernel_launch(void* const* d_in, const int* in_sizes, int n_in,
                              void* d_out, int out_size, void* d_ws, size_t ws_size,
                              hipStream_t stream) {
    (void)in_sizes; (void)n_in; (void)out_size; (void)ws_size;
    const float* x     = (const float*)d_in[0];
    const float* edge0 = (const float*)d_in[1];
    const int*   mask  = (const int*)d_in[2];
    const float* W1m   = (const float*)d_in[3];
    const float* b1m   = (const float*)d_in[4];
    const float* W2m   = (const float*)d_in[5];
    const float* b2m   = (const float*)d_in[6];
    const float* W1u   = (const float*)d_in[7];
    const float* b1u   = (const float*)d_in[8];
    const float* W2u   = (const float*)d_in[9];
    const float* b2u   = (const float*)d_in[10];
    const float* gamma = (const float*)d_in[11];
    const float* beta  = (const float*)d_in[12];

    float* P    = (float*)d_ws;                 // 2048*128 f32 = 1 MB
    float* Qn   = P + 2048 * 128;               // 2048*128 f32 = 1 MB (row-major)
    u16*   W1cp = (u16*)(Qn + 2048 * 128);      // 16384 bf16 = 32 KB

    float* o = (float*)d_out;

    prep_kernel<<<dim3(1025), dim3(256), 0, stream>>>(x, W1m, b1m, P, Qn, W1cp);
    fused_kernel<<<dim3(2048), dim3(256), 0, stream>>>(
        x, edge0, mask, W2m, b2m, W1u, b1u, W2u, b2u, gamma, beta,
        P, Qn, W1cp, o);
}